// Round 1
// baseline (1513.933 us; speedup 1.0000x reference)
//
#include <hip/hip_runtime.h>
#include <cstdint>
#include <cstddef>

#define WAVE 64

// ---------------------------------------------------------------------------
// deg[i] = 1.0 (self-loop weight), cnt[i] = 0
__global__ void init_kernel(float* __restrict__ deg, int* __restrict__ cnt, int n) {
    int i = blockIdx.x * blockDim.x + threadIdx.x;
    if (i < n) { deg[i] = 1.0f; cnt[i] = 0; }
}

// deg[col[e]] += ew[e];  cnt[col[e]] += 1
__global__ void hist_kernel(const int* __restrict__ col, const float* __restrict__ ew,
                            float* __restrict__ deg, int* __restrict__ cnt, int E) {
    int e = blockIdx.x * blockDim.x + threadIdx.x;
    if (e < E) {
        int c = col[e];
        atomicAdd(&deg[c], ew[e]);
        atomicAdd(&cnt[c], 1);
    }
}

// in-place: dis[i] = rsqrt(deg[i])   (deg >= 1 always, self-loop included)
__global__ void dis_kernel(float* __restrict__ deg, int n) {
    int i = blockIdx.x * blockDim.x + threadIdx.x;
    if (i < n) deg[i] = rsqrtf(deg[i]);
}

// single-block exclusive scan of cnt[0..n) -> row_ptr[0..n], cursor copy
__global__ void scan_kernel(const int* __restrict__ cnt, int* __restrict__ row_ptr,
                            int* __restrict__ cursor, int n) {
    __shared__ int lds[1024];
    const int T = threadIdx.x;
    const int chunk = (n + 1023) >> 10;
    const int base = T * chunk;
    int s = 0;
    for (int i = 0; i < chunk; i++) {
        int idx = base + i;
        if (idx < n) s += cnt[idx];
    }
    lds[T] = s;
    __syncthreads();
    for (int off = 1; off < 1024; off <<= 1) {
        int v = (T >= off) ? lds[T - off] : 0;
        __syncthreads();
        lds[T] += v;
        __syncthreads();
    }
    int run = lds[T] - s;  // exclusive prefix for this thread's chunk
    for (int i = 0; i < chunk; i++) {
        int idx = base + i;
        if (idx < n) {
            row_ptr[idx] = run;
            cursor[idx]  = run;
            run += cnt[idx];
        }
    }
    if (T == 1023) row_ptr[n] = lds[1023];
}

// bucket edges by destination: csr[pos] = {src, bits(ew)}
__global__ void fill_kernel(const int* __restrict__ row, const int* __restrict__ col,
                            const float* __restrict__ ew, int* __restrict__ cursor,
                            uint2* __restrict__ csr, int E) {
    int e = blockIdx.x * blockDim.x + threadIdx.x;
    if (e < E) {
        int c = col[e];
        int p = atomicAdd(&cursor[c], 1);
        csr[p] = make_uint2((unsigned)row[e], __float_as_uint(ew[e]));
    }
}

// t1 = X @ W1   ([N,128] @ [128,12]); one wave per node
__global__ void lin1_kernel(const float* __restrict__ X, const float* __restrict__ W1,
                            float* __restrict__ t1, int n) {
    int node = (int)((blockIdx.x * (size_t)blockDim.x + threadIdx.x) >> 6);
    int lane = threadIdx.x & 63;
    if (node >= n) return;
    const float* xr = X + (size_t)node * 128;
    float x0 = xr[lane];
    float x1 = xr[lane + 64];
    float res[12];
#pragma unroll
    for (int o = 0; o < 12; o++) {
        float p = x0 * W1[lane * 12 + o] + x1 * W1[(lane + 64) * 12 + o];
#pragma unroll
        for (int off = 32; off > 0; off >>= 1) p += __shfl_xor(p, off, WAVE);
        res[o] = p;
    }
    if (lane == 0) {
        float4* o4 = (float4*)(t1 + (size_t)node * 12);
        o4[0] = make_float4(res[0], res[1], res[2], res[3]);
        o4[1] = make_float4(res[4], res[5], res[6], res[7]);
        o4[2] = make_float4(res[8], res[9], res[10], res[11]);
    }
}

// Pull aggregation, one wave per destination node.
//   acc = sum_{e in CSR[node]} norm_e * hin[src_e]     (FIRST: compute+store norm)
//   v   = relu(acc + dis[node]^2 * hin[node] + b_this)
//   !LAST: hout[node] = v @ W_next   (padded to SOUT)
//   LAST : hout[node] = sigmoid(v . W_next + b_next)
template <int DIN, int SIN, int DOUT, int SOUT, bool FIRST, bool LAST>
__global__ void agg_kernel(const int* __restrict__ row_ptr, uint2* __restrict__ csr,
                           const float* __restrict__ dis, const float* __restrict__ hin,
                           const float* __restrict__ b_this, const float* __restrict__ W_next,
                           const float* __restrict__ b_next, float* __restrict__ hout, int n) {
    int node = (int)((blockIdx.x * (size_t)blockDim.x + threadIdx.x) >> 6);
    int lane = threadIdx.x & 63;
    if (node >= n) return;
    int start = row_ptr[node];
    int end   = row_ptr[node + 1];
    float dn  = dis[node];
    float acc[DIN];
#pragma unroll
    for (int d = 0; d < DIN; d++) acc[d] = 0.f;

    for (int e = start + lane; e < end; e += WAVE) {
        uint2 ev = csr[e];
        int r = (int)ev.x;
        float norm;
        if constexpr (FIRST) {
            norm = dn * __uint_as_float(ev.y) * dis[r];
            csr[e].y = __float_as_uint(norm);
        } else {
            norm = __uint_as_float(ev.y);
        }
        const float* hr = hin + (size_t)r * SIN;
        if constexpr (DIN == 12) {
            const float4* p = (const float4*)hr;
            float4 a = p[0], b = p[1], c = p[2];
            acc[0] += norm * a.x;  acc[1] += norm * a.y;  acc[2]  += norm * a.z;  acc[3]  += norm * a.w;
            acc[4] += norm * b.x;  acc[5] += norm * b.y;  acc[6]  += norm * b.z;  acc[7]  += norm * b.w;
            acc[8] += norm * c.x;  acc[9] += norm * c.y;  acc[10] += norm * c.z;  acc[11] += norm * c.w;
        } else if constexpr (DIN == 6) {
            float4 a = *(const float4*)hr;
            float2 b = *(const float2*)(hr + 4);
            acc[0] += norm * a.x;  acc[1] += norm * a.y;  acc[2] += norm * a.z;
            acc[3] += norm * a.w;  acc[4] += norm * b.x;  acc[5] += norm * b.y;
        } else {  // DIN == 3
            float4 a = *(const float4*)hr;
            acc[0] += norm * a.x;  acc[1] += norm * a.y;  acc[2] += norm * a.z;
        }
    }

#pragma unroll
    for (int d = 0; d < DIN; d++) {
#pragma unroll
        for (int off = 32; off > 0; off >>= 1) acc[d] += __shfl_xor(acc[d], off, WAVE);
    }

    if (lane == 0) {
        float s2 = dn * dn;
        const float* hn = hin + (size_t)node * SIN;
        float v[DIN];
#pragma unroll
        for (int d = 0; d < DIN; d++)
            v[d] = fmaxf(acc[d] + s2 * hn[d] + b_this[d], 0.f);
        if constexpr (!LAST) {
            float o[DOUT];
#pragma unroll
            for (int oo = 0; oo < DOUT; oo++) {
                float s = 0.f;
#pragma unroll
                for (int d = 0; d < DIN; d++) s += v[d] * W_next[d * DOUT + oo];
                o[oo] = s;
            }
            float* op = hout + (size_t)node * SOUT;
            if constexpr (DOUT == 6) {
                *(float4*)op       = make_float4(o[0], o[1], o[2], o[3]);
                *(float4*)(op + 4) = make_float4(o[4], o[5], 0.f, 0.f);
            } else {  // DOUT == 3, SOUT == 4
                *(float4*)op = make_float4(o[0], o[1], o[2], 0.f);
            }
        } else {
            float z = b_next[0];
#pragma unroll
            for (int d = 0; d < DIN; d++) z += v[d] * W_next[d];
            hout[node] = 1.0f / (1.0f + expf(-z));
        }
    }
}

// ---------------------------------------------------------------------------
extern "C" void kernel_launch(void* const* d_in, const int* in_sizes, int n_in,
                              void* d_out, int out_size, void* d_ws, size_t ws_size,
                              hipStream_t stream) {
    const float* X  = (const float*)d_in[0];
    const int*   ei = (const int*)d_in[1];
    const float* ew = (const float*)d_in[2];
    const float* W1 = (const float*)d_in[3];
    const float* b1 = (const float*)d_in[4];
    const float* W2 = (const float*)d_in[5];
    const float* b2 = (const float*)d_in[6];
    const float* W3 = (const float*)d_in[7];
    const float* b3 = (const float*)d_in[8];
    const float* Wl = (const float*)d_in[9];
    const float* bl = (const float*)d_in[10];
    float* out = (float*)d_out;

    const int N = in_sizes[0] / 128;
    const int E = in_sizes[1] / 2;
    const int* row = ei;
    const int* col = ei + E;

    char* ws = (char*)d_ws;
    size_t off = 0;
    auto carve = [&](size_t bytes) -> void* {
        void* p = ws + off;
        off += (bytes + 255) & ~(size_t)255;
        return p;
    };
    float* dis     = (float*)carve((size_t)N * 4);
    int*   cnt     = (int*)  carve((size_t)N * 4);
    int*   row_ptr = (int*)  carve((size_t)(N + 1) * 4);
    int*   cursor  = (int*)  carve((size_t)N * 4);
    uint2* csr     = (uint2*)carve((size_t)E * 8);
    float* t1      = (float*)carve((size_t)N * 12 * 4);
    float* t2      = (float*)carve((size_t)N * 8 * 4);
    float* t3      = (float*)carve((size_t)N * 4 * 4);
    (void)ws_size; (void)n_in; (void)out_size;

    const int bN = (N + 255) / 256;
    const int bE = (E + 255) / 256;
    const int bW = (N + 3) / 4;  // wave-per-node, 4 waves/block

    init_kernel<<<bN, 256, 0, stream>>>(dis, cnt, N);
    hist_kernel<<<bE, 256, 0, stream>>>(col, ew, dis, cnt, E);
    dis_kernel<<<bN, 256, 0, stream>>>(dis, N);
    scan_kernel<<<1, 1024, 0, stream>>>(cnt, row_ptr, cursor, N);
    fill_kernel<<<bE, 256, 0, stream>>>(row, col, ew, cursor, csr, E);
    lin1_kernel<<<bW, 256, 0, stream>>>(X, W1, t1, N);
    agg_kernel<12, 12, 6, 8, true,  false><<<bW, 256, 0, stream>>>(row_ptr, csr, dis, t1, b1, W2, nullptr, t2, N);
    agg_kernel< 6,  8, 3, 4, false, false><<<bW, 256, 0, stream>>>(row_ptr, csr, dis, t2, b2, W3, nullptr, t3, N);
    agg_kernel< 3,  4, 1, 1, false, true ><<<bW, 256, 0, stream>>>(row_ptr, csr, dis, t3, b3, Wl, bl, out, N);
}

// Round 2
// 1284.029 us; speedup vs baseline: 1.1790x; 1.1790x over previous
//
#include <hip/hip_runtime.h>
#include <cstdint>
#include <cstddef>

// ---------------------------------------------------------------------------
__global__ void zero_kernel(int* __restrict__ cnt, int n) {
    int i = blockIdx.x * blockDim.x + threadIdx.x;
    if (i < n) cnt[i] = 0;
}

// rank[e] = old count of destination; cnt accumulates in-degree.
// ONE atomic per edge — the atomic's return value doubles as the slot index,
// which makes the later fill pass atomic-free.
__global__ void hist_rank_kernel(const int* __restrict__ col, int* __restrict__ cnt,
                                 int* __restrict__ rank, int E) {
    int e = blockIdx.x * blockDim.x + threadIdx.x;
    if (e < E) rank[e] = atomicAdd(&cnt[col[e]], 1);
}

// single-block exclusive scan of cnt[0..n) -> row_ptr[0..n]
__global__ void scan_kernel(const int* __restrict__ cnt, int* __restrict__ row_ptr, int n) {
    __shared__ int lds[1024];
    const int T = threadIdx.x;
    const int chunk = (n + 1023) >> 10;
    const int base = T * chunk;
    int s = 0;
    for (int i = 0; i < chunk; i++) {
        int idx = base + i;
        if (idx < n) s += cnt[idx];
    }
    lds[T] = s;
    __syncthreads();
    for (int off = 1; off < 1024; off <<= 1) {
        int v = (T >= off) ? lds[T - off] : 0;
        __syncthreads();
        lds[T] += v;
        __syncthreads();
    }
    int run = lds[T] - s;  // exclusive prefix for this thread's chunk
    for (int i = 0; i < chunk; i++) {
        int idx = base + i;
        if (idx < n) {
            row_ptr[idx] = run;
            run += cnt[idx];
        }
    }
    if (T == 1023) row_ptr[n] = lds[1023];
}

// atomic-free bucket fill: position = row_ptr[dst] + rank[e]
__global__ void fill_kernel(const int* __restrict__ row, const int* __restrict__ col,
                            const float* __restrict__ ew, const int* __restrict__ row_ptr,
                            const int* __restrict__ rank, uint2* __restrict__ csr, int E) {
    int e = blockIdx.x * blockDim.x + threadIdx.x;
    if (e < E) {
        int p = row_ptr[col[e]] + rank[e];
        csr[p] = make_uint2((unsigned)row[e], __float_as_uint(ew[e]));
    }
}

// dis[i] = rsqrt(1 + sum of edge weights into i)  — atomic-free pull over CSR
__global__ void deg_kernel(const uint2* __restrict__ csr, const int* __restrict__ row_ptr,
                           float* __restrict__ dis, int n) {
    int i = blockIdx.x * blockDim.x + threadIdx.x;
    if (i >= n) return;
    int s = row_ptr[i], e = row_ptr[i + 1];
    float d = 1.0f;
    for (int k = s; k < e; ++k) d += __uint_as_float(csr[k].y);
    dis[i] = rsqrtf(d);
}

// t1 = X @ W1   ([N,128] @ [128,12]); one wave per node
__global__ void lin1_kernel(const float* __restrict__ X, const float* __restrict__ W1,
                            float* __restrict__ t1, int n) {
    int node = (int)((blockIdx.x * (size_t)blockDim.x + threadIdx.x) >> 6);
    int lane = threadIdx.x & 63;
    if (node >= n) return;
    const float* xr = X + (size_t)node * 128;
    float x0 = xr[lane];
    float x1 = xr[lane + 64];
    float res[12];
#pragma unroll
    for (int o = 0; o < 12; o++) {
        float p = x0 * W1[lane * 12 + o] + x1 * W1[(lane + 64) * 12 + o];
#pragma unroll
        for (int off = 32; off > 0; off >>= 1) p += __shfl_xor(p, off, 64);
        res[o] = p;
    }
    if (lane == 0) {
        float4* o4 = (float4*)(t1 + (size_t)node * 12);
        o4[0] = make_float4(res[0], res[1], res[2], res[3]);
        o4[1] = make_float4(res[4], res[5], res[6], res[7]);
        o4[2] = make_float4(res[8], res[9], res[10], res[11]);
    }
}

// Pull aggregation, ONE THREAD per destination node (serial row walk — no
// shuffles; CSR reads hit the same 64B line 8x in a row per thread).
//   acc = sum_{e in row} norm_e * hin[src_e]   (FIRST: compute norm, store it)
//   v   = relu(acc + dis[node]^2 * hin[node] + b_this)
//   !LAST: hout[node] = v @ W_next (padded to SOUT);  LAST: sigmoid(v.W + b)
template <int DIN, int SIN, int DOUT, int SOUT, bool FIRST, bool LAST>
__global__ void agg_kernel(const int* __restrict__ row_ptr, uint2* __restrict__ csr,
                           const float* __restrict__ dis, const float* __restrict__ hin,
                           const float* __restrict__ b_this, const float* __restrict__ W_next,
                           const float* __restrict__ b_next, float* __restrict__ hout, int n) {
    int node = blockIdx.x * blockDim.x + threadIdx.x;
    if (node >= n) return;
    int start = row_ptr[node];
    int end   = row_ptr[node + 1];
    float dn  = dis[node];
    float acc[DIN];
#pragma unroll
    for (int d = 0; d < DIN; d++) acc[d] = 0.f;

    for (int e = start; e < end; ++e) {
        uint2 ev = csr[e];
        int r = (int)ev.x;
        float norm;
        if constexpr (FIRST) {
            norm = dn * __uint_as_float(ev.y) * dis[r];
            csr[e].y = __float_as_uint(norm);
        } else {
            norm = __uint_as_float(ev.y);
        }
        const float* hr = hin + (size_t)r * SIN;
        if constexpr (DIN == 12) {
            const float4* p = (const float4*)hr;
            float4 a = p[0], b = p[1], c = p[2];
            acc[0] += norm * a.x;  acc[1] += norm * a.y;  acc[2]  += norm * a.z;  acc[3]  += norm * a.w;
            acc[4] += norm * b.x;  acc[5] += norm * b.y;  acc[6]  += norm * b.z;  acc[7]  += norm * b.w;
            acc[8] += norm * c.x;  acc[9] += norm * c.y;  acc[10] += norm * c.z;  acc[11] += norm * c.w;
        } else if constexpr (DIN == 6) {
            float4 a = *(const float4*)hr;
            float2 b = *(const float2*)(hr + 4);
            acc[0] += norm * a.x;  acc[1] += norm * a.y;  acc[2] += norm * a.z;
            acc[3] += norm * a.w;  acc[4] += norm * b.x;  acc[5] += norm * b.y;
        } else {  // DIN == 3
            float4 a = *(const float4*)hr;
            acc[0] += norm * a.x;  acc[1] += norm * a.y;  acc[2] += norm * a.z;
        }
    }

    float s2 = dn * dn;
    const float* hn = hin + (size_t)node * SIN;
    float v[DIN];
#pragma unroll
    for (int d = 0; d < DIN; d++)
        v[d] = fmaxf(acc[d] + s2 * hn[d] + b_this[d], 0.f);
    if constexpr (!LAST) {
        float o[DOUT];
#pragma unroll
        for (int oo = 0; oo < DOUT; oo++) {
            float s = 0.f;
#pragma unroll
            for (int d = 0; d < DIN; d++) s += v[d] * W_next[d * DOUT + oo];
            o[oo] = s;
        }
        float* op = hout + (size_t)node * SOUT;
        if constexpr (DOUT == 6) {
            *(float4*)op       = make_float4(o[0], o[1], o[2], o[3]);
            *(float4*)(op + 4) = make_float4(o[4], o[5], 0.f, 0.f);
        } else {  // DOUT == 3, SOUT == 4
            *(float4*)op = make_float4(o[0], o[1], o[2], 0.f);
        }
    } else {
        float z = b_next[0];
#pragma unroll
        for (int d = 0; d < DIN; d++) z += v[d] * W_next[d];
        hout[node] = 1.0f / (1.0f + expf(-z));
    }
}

// ---------------------------------------------------------------------------
extern "C" void kernel_launch(void* const* d_in, const int* in_sizes, int n_in,
                              void* d_out, int out_size, void* d_ws, size_t ws_size,
                              hipStream_t stream) {
    const float* X  = (const float*)d_in[0];
    const int*   ei = (const int*)d_in[1];
    const float* ew = (const float*)d_in[2];
    const float* W1 = (const float*)d_in[3];
    const float* b1 = (const float*)d_in[4];
    const float* W2 = (const float*)d_in[5];
    const float* b2 = (const float*)d_in[6];
    const float* W3 = (const float*)d_in[7];
    const float* b3 = (const float*)d_in[8];
    const float* Wl = (const float*)d_in[9];
    const float* bl = (const float*)d_in[10];
    float* out = (float*)d_out;

    const int N = in_sizes[0] / 128;
    const int E = in_sizes[1] / 2;
    const int* row = ei;
    const int* col = ei + E;

    char* ws = (char*)d_ws;
    size_t off = 0;
    auto carve = [&](size_t bytes) -> void* {
        void* p = ws + off;
        off += (bytes + 255) & ~(size_t)255;
        return p;
    };
    int*   cnt     = (int*)  carve((size_t)N * 4);
    int*   row_ptr = (int*)  carve((size_t)(N + 1) * 4);
    int*   rank    = (int*)  carve((size_t)E * 4);
    uint2* csr     = (uint2*)carve((size_t)E * 8);
    float* dis     = (float*)carve((size_t)N * 4);
    float* t1      = (float*)carve((size_t)N * 12 * 4);
    float* t2      = (float*)carve((size_t)N * 8 * 4);
    float* t3      = (float*)carve((size_t)N * 4 * 4);
    (void)ws_size; (void)n_in; (void)out_size;

    const int bN = (N + 255) / 256;
    const int bE = (E + 255) / 256;
    const int bW = (N + 3) / 4;  // wave-per-node (lin1), 4 waves/block

    zero_kernel<<<bN, 256, 0, stream>>>(cnt, N);
    hist_rank_kernel<<<bE, 256, 0, stream>>>(col, cnt, rank, E);
    scan_kernel<<<1, 1024, 0, stream>>>(cnt, row_ptr, N);
    fill_kernel<<<bE, 256, 0, stream>>>(row, col, ew, row_ptr, rank, csr, E);
    deg_kernel<<<bN, 256, 0, stream>>>(csr, row_ptr, dis, N);
    lin1_kernel<<<bW, 256, 0, stream>>>(X, W1, t1, N);
    agg_kernel<12, 12, 6, 8, true,  false><<<bN, 256, 0, stream>>>(row_ptr, csr, dis, t1, b1, W2, nullptr, t2, N);
    agg_kernel< 6,  8, 3, 4, false, false><<<bN, 256, 0, stream>>>(row_ptr, csr, dis, t2, b2, W3, nullptr, t3, N);
    agg_kernel< 3,  4, 1, 1, false, true ><<<bN, 256, 0, stream>>>(row_ptr, csr, dis, t3, b3, Wl, bl, out, N);
}

// Round 3
// 702.884 us; speedup vs baseline: 2.1539x; 1.8268x over previous
//
#include <hip/hip_runtime.h>
#include <cstdint>
#include <cstddef>

#define RANGE   128        // nodes per bucket
#define RSHIFT  7
#define MAXBUCK 800        // >= ceil(N/RANGE); N=100K -> 782
#define CH      16384      // edges per partition block
#define PAD     16         // pad global counters to one 64B line each

// ---------------------------------------------------------------------------
__global__ void zero_pad_kernel(int* __restrict__ p, int n) {
    int i = blockIdx.x * blockDim.x + threadIdx.x;
    if (i < n) p[i * PAD] = 0;
}

// per-block LDS histogram of col>>7, merged with ~nbuck global atomics/block
__global__ void count_kernel(const int* __restrict__ col, int* __restrict__ bcnt,
                             int nbuck, int E) {
    __shared__ int lcnt[MAXBUCK];
    int tid = threadIdx.x;
    for (int i = tid; i < nbuck; i += blockDim.x) lcnt[i] = 0;
    __syncthreads();
    int base = blockIdx.x * CH;
    int end  = min(E, base + CH);
    for (int e = base + tid; e < end; e += blockDim.x)
        atomicAdd(&lcnt[col[e] >> RSHIFT], 1);
    __syncthreads();
    for (int i = tid; i < nbuck; i += blockDim.x)
        if (lcnt[i]) atomicAdd(&bcnt[i * PAD], lcnt[i]);
}

// exclusive scan of bucket counts (nbuck <= 1024), init padded cursors
__global__ void scan_buckets_kernel(const int* __restrict__ bcnt, int* __restrict__ bbase,
                                    int* __restrict__ cursor, int* __restrict__ row_ptr,
                                    int nbuck, int N, int E) {
    __shared__ int lds[1024];
    int T = threadIdx.x;
    int s = (T < nbuck) ? bcnt[T * PAD] : 0;
    lds[T] = s;
    __syncthreads();
    for (int off = 1; off < 1024; off <<= 1) {
        int v = (T >= off) ? lds[T - off] : 0;
        __syncthreads();
        lds[T] += v;
        __syncthreads();
    }
    int excl = lds[T] - s;
    if (T < nbuck) { bbase[T] = excl; cursor[T * PAD] = excl; }
    if (T == 0)    { bbase[nbuck] = E; row_ptr[N] = E; }
}

// scatter edges into bucket-grouped records; per-edge offsets via LDS cursors,
// only ~nbuck global atomics per block.  record = {row | col_low<<17, ew}
__global__ void scatter_kernel(const int* __restrict__ row, const int* __restrict__ col,
                               const float* __restrict__ ew, int* __restrict__ cursor,
                               uint2* __restrict__ part, int nbuck, int E) {
    __shared__ int lcnt[MAXBUCK];
    __shared__ int lbase[MAXBUCK];
    int tid = threadIdx.x;
    for (int i = tid; i < nbuck; i += blockDim.x) lcnt[i] = 0;
    __syncthreads();
    int base = blockIdx.x * CH;
    int end  = min(E, base + CH);
    for (int e = base + tid; e < end; e += blockDim.x)
        atomicAdd(&lcnt[col[e] >> RSHIFT], 1);
    __syncthreads();
    for (int i = tid; i < nbuck; i += blockDim.x) {
        int c = lcnt[i];
        lbase[i] = c ? atomicAdd(&cursor[i * PAD], c) : 0;
        lcnt[i] = 0;
    }
    __syncthreads();
    for (int e = base + tid; e < end; e += blockDim.x) {
        int c = col[e];
        int b = c >> RSHIFT;
        int off = atomicAdd(&lcnt[b], 1);
        part[lbase[b] + off] =
            make_uint2((unsigned)row[e] | ((unsigned)(c & (RANGE - 1)) << 17),
                       __float_as_uint(ew[e]));
    }
}

// one block per bucket: exact per-node CSR + row_ptr + dis, all in LDS
__global__ void bucket_csr_kernel(const uint2* __restrict__ part, const int* __restrict__ bbase,
                                  int* __restrict__ row_ptr, float* __restrict__ dis,
                                  uint2* __restrict__ csr, int N) {
    __shared__ int   scnt[RANGE];
    __shared__ float sdeg[RANGE];
    __shared__ int   sscan[RANGE];
    int b = blockIdx.x;
    int tid = threadIdx.x;
    int s = bbase[b], t = bbase[b + 1];
    if (tid < RANGE) { scnt[tid] = 0; sdeg[tid] = 1.0f; }  // deg starts at self-loop weight
    __syncthreads();
    for (int e = s + tid; e < t; e += blockDim.x) {
        uint2 r = part[e];
        int c = (r.x >> 17) & (RANGE - 1);
        atomicAdd(&scnt[c], 1);
        atomicAdd(&sdeg[c], __uint_as_float(r.y));
    }
    __syncthreads();
    int cnt_t = 0;
    if (tid < RANGE) { cnt_t = scnt[tid]; sscan[tid] = cnt_t; }
    __syncthreads();
    for (int off = 1; off < RANGE; off <<= 1) {
        int v = 0;
        if (tid < RANGE && tid >= off) v = sscan[tid - off];
        __syncthreads();
        if (tid < RANGE) sscan[tid] += v;
        __syncthreads();
    }
    if (tid < RANGE) {
        int excl = sscan[tid] - cnt_t;
        int node = b * RANGE + tid;
        if (node < N) {
            row_ptr[node] = s + excl;
            dis[node] = rsqrtf(sdeg[tid]);
        }
        scnt[tid] = excl;  // reuse as within-bucket cursor
    }
    __syncthreads();
    for (int e = s + tid; e < t; e += blockDim.x) {
        uint2 r = part[e];
        int c = (r.x >> 17) & (RANGE - 1);
        int off = atomicAdd(&scnt[c], 1);
        csr[s + off] = make_uint2(r.x & 0x1FFFFu, r.y);
    }
}

// t1 = X @ W1   ([N,128] @ [128,12]); one wave per node
__global__ void lin1_kernel(const float* __restrict__ X, const float* __restrict__ W1,
                            float* __restrict__ t1, int n) {
    int node = (int)((blockIdx.x * (size_t)blockDim.x + threadIdx.x) >> 6);
    int lane = threadIdx.x & 63;
    if (node >= n) return;
    const float* xr = X + (size_t)node * 128;
    float x0 = xr[lane];
    float x1 = xr[lane + 64];
    float res[12];
#pragma unroll
    for (int o = 0; o < 12; o++) {
        float p = x0 * W1[lane * 12 + o] + x1 * W1[(lane + 64) * 12 + o];
#pragma unroll
        for (int off = 32; off > 0; off >>= 1) p += __shfl_xor(p, off, 64);
        res[o] = p;
    }
    if (lane == 0) {
        float4* o4 = (float4*)(t1 + (size_t)node * 12);
        o4[0] = make_float4(res[0], res[1], res[2], res[3]);
        o4[1] = make_float4(res[4], res[5], res[6], res[7]);
        o4[2] = make_float4(res[8], res[9], res[10], res[11]);
    }
}

// Pull aggregation, 8 lanes per destination node: coalesced 64B CSR line per
// group, 800K threads (full occupancy), 3-step shuffle reduction.
template <int DIN, int SIN, int DOUT, int SOUT, bool FIRST, bool LAST>
__global__ void agg_kernel(const int* __restrict__ row_ptr, uint2* __restrict__ csr,
                           const float* __restrict__ dis, const float* __restrict__ hin,
                           const float* __restrict__ b_this, const float* __restrict__ W_next,
                           const float* __restrict__ b_next, float* __restrict__ hout, int n) {
    int gt   = blockIdx.x * blockDim.x + threadIdx.x;
    int node = gt >> 3;
    int sub  = gt & 7;
    if (node >= n) return;
    int start = row_ptr[node];
    int end   = row_ptr[node + 1];
    float dn  = dis[node];
    float acc[DIN];
#pragma unroll
    for (int d = 0; d < DIN; d++) acc[d] = 0.f;

    for (int e = start + sub; e < end; e += 8) {
        uint2 ev = csr[e];
        int r = (int)ev.x;
        float norm;
        if constexpr (FIRST) {
            norm = dn * __uint_as_float(ev.y) * dis[r];
            csr[e].y = __float_as_uint(norm);
        } else {
            norm = __uint_as_float(ev.y);
        }
        const float* hr = hin + (size_t)r * SIN;
        if constexpr (DIN == 12) {
            const float4* p = (const float4*)hr;
            float4 a = p[0], b = p[1], c = p[2];
            acc[0] += norm * a.x;  acc[1] += norm * a.y;  acc[2]  += norm * a.z;  acc[3]  += norm * a.w;
            acc[4] += norm * b.x;  acc[5] += norm * b.y;  acc[6]  += norm * b.z;  acc[7]  += norm * b.w;
            acc[8] += norm * c.x;  acc[9] += norm * c.y;  acc[10] += norm * c.z;  acc[11] += norm * c.w;
        } else if constexpr (DIN == 6) {
            float4 a = *(const float4*)hr;
            float2 b = *(const float2*)(hr + 4);
            acc[0] += norm * a.x;  acc[1] += norm * a.y;  acc[2] += norm * a.z;
            acc[3] += norm * a.w;  acc[4] += norm * b.x;  acc[5] += norm * b.y;
        } else {  // DIN == 3
            float4 a = *(const float4*)hr;
            acc[0] += norm * a.x;  acc[1] += norm * a.y;  acc[2] += norm * a.z;
        }
    }

#pragma unroll
    for (int d = 0; d < DIN; d++) {
        acc[d] += __shfl_xor(acc[d], 1, 64);
        acc[d] += __shfl_xor(acc[d], 2, 64);
        acc[d] += __shfl_xor(acc[d], 4, 64);
    }

    if (sub == 0) {
        float s2 = dn * dn;
        const float* hn = hin + (size_t)node * SIN;
        float v[DIN];
#pragma unroll
        for (int d = 0; d < DIN; d++)
            v[d] = fmaxf(acc[d] + s2 * hn[d] + b_this[d], 0.f);
        if constexpr (!LAST) {
            float o[DOUT];
#pragma unroll
            for (int oo = 0; oo < DOUT; oo++) {
                float s = 0.f;
#pragma unroll
                for (int d = 0; d < DIN; d++) s += v[d] * W_next[d * DOUT + oo];
                o[oo] = s;
            }
            float* op = hout + (size_t)node * SOUT;
            if constexpr (DOUT == 6) {
                *(float4*)op       = make_float4(o[0], o[1], o[2], o[3]);
                *(float4*)(op + 4) = make_float4(o[4], o[5], 0.f, 0.f);
            } else {  // DOUT == 3, SOUT == 4
                *(float4*)op = make_float4(o[0], o[1], o[2], 0.f);
            }
        } else {
            float z = b_next[0];
#pragma unroll
            for (int d = 0; d < DIN; d++) z += v[d] * W_next[d];
            hout[node] = 1.0f / (1.0f + expf(-z));
        }
    }
}

// ---------------------------------------------------------------------------
extern "C" void kernel_launch(void* const* d_in, const int* in_sizes, int n_in,
                              void* d_out, int out_size, void* d_ws, size_t ws_size,
                              hipStream_t stream) {
    const float* X  = (const float*)d_in[0];
    const int*   ei = (const int*)d_in[1];
    const float* ew = (const float*)d_in[2];
    const float* W1 = (const float*)d_in[3];
    const float* b1 = (const float*)d_in[4];
    const float* W2 = (const float*)d_in[5];
    const float* b2 = (const float*)d_in[6];
    const float* W3 = (const float*)d_in[7];
    const float* b3 = (const float*)d_in[8];
    const float* Wl = (const float*)d_in[9];
    const float* bl = (const float*)d_in[10];
    float* out = (float*)d_out;

    const int N = in_sizes[0] / 128;
    const int E = in_sizes[1] / 2;
    const int* row = ei;
    const int* col = ei + E;
    const int nbuck = (N + RANGE - 1) >> RSHIFT;

    char* ws = (char*)d_ws;
    size_t off = 0;
    auto carve = [&](size_t bytes) -> void* {
        void* p = ws + off;
        off += (bytes + 255) & ~(size_t)255;
        return p;
    };
    int*   bcnt    = (int*)  carve((size_t)MAXBUCK * PAD * 4);
    int*   cursor  = (int*)  carve((size_t)MAXBUCK * PAD * 4);
    int*   bbase   = (int*)  carve((size_t)(MAXBUCK + 1) * 4);
    int*   row_ptr = (int*)  carve((size_t)(N + 1) * 4);
    float* dis     = (float*)carve((size_t)N * 4);
    uint2* part    = (uint2*)carve((size_t)E * 8);
    uint2* csr     = (uint2*)carve((size_t)E * 8);
    // t1/t2/t3 alias `part` (dead after bucket_csr_kernel; stream order keeps this safe)
    float* t1 = (float*)part;
    float* t2 = t1 + (size_t)N * 12;
    float* t3 = t2 + (size_t)N * 8;
    (void)ws_size; (void)n_in; (void)out_size;

    const int bP = (E + CH - 1) / CH;              // partition blocks
    const int bW = (N + 3) / 4;                    // lin1: wave per node
    const int bA = ((size_t)N * 8 + 255) / 256;    // agg: 8 lanes per node

    zero_pad_kernel<<<(nbuck + 255) / 256, 256, 0, stream>>>(bcnt, nbuck);
    count_kernel<<<bP, 256, 0, stream>>>(col, bcnt, nbuck, E);
    scan_buckets_kernel<<<1, 1024, 0, stream>>>(bcnt, bbase, cursor, row_ptr, nbuck, N, E);
    scatter_kernel<<<bP, 256, 0, stream>>>(row, col, ew, cursor, part, nbuck, E);
    bucket_csr_kernel<<<nbuck, 256, 0, stream>>>(part, bbase, row_ptr, dis, csr, N);
    lin1_kernel<<<bW, 256, 0, stream>>>(X, W1, t1, N);
    agg_kernel<12, 12, 6, 8, true,  false><<<bA, 256, 0, stream>>>(row_ptr, csr, dis, t1, b1, W2, nullptr, t2, N);
    agg_kernel< 6,  8, 3, 4, false, false><<<bA, 256, 0, stream>>>(row_ptr, csr, dis, t2, b2, W3, nullptr, t3, N);
    agg_kernel< 3,  4, 1, 1, false, true ><<<bA, 256, 0, stream>>>(row_ptr, csr, dis, t3, b3, Wl, bl, out, N);
}